// Round 6
// baseline (377.208 us; speedup 1.0000x reference)
//
#include <hip/hip_runtime.h>
#include <stdint.h>

// Problem constants
#define BB   8
#define CC   64
#define HH   256
#define WW   256
#define HWSZ (HH*WW)              // 65536
#define CHW  (CC*HH*WW)           // 4194304
#define GROUPELEMS (8*HWSZ)       // 524288 (channels-per-group=8)
#define EPSV 1e-5f

// ws layout (bytes)
#define WS_PART_OFF   0           // 512 x float2   (4 KiB)
#define WS_AFF_OFF    4096        // 512 x float2   (4 KiB)
#define WS_WFRAG_OFF  8192        // 4096 x uint32  (16 KiB)  A-fragment packed weights

typedef __attribute__((ext_vector_type(8))) short bf16x8;
typedef __attribute__((ext_vector_type(4))) float f32x4;
typedef __attribute__((ext_vector_type(4))) unsigned int u32x4;
union U32x4 { uint32_t u[4]; uint4 q; bf16x8 v; u32x4 nv; };

__device__ __forceinline__ uint32_t f32_to_bf16_bits(float f) {
    uint32_t u = __float_as_uint(f);
    u += 0x7fffu + ((u >> 16) & 1u);   // RNE
    return u >> 16;
}

// ---------------- K1: per-slice partial sums for GroupNorm stats ------------
// Fused: blocks 0..15 also pack fp32 weights into MFMA A-fragment layout.
// wfrag layout: M = 128 (gate rows 0..63, upd rows 64..127), K = 64.
// lane l holds A[m=16mt+(l&15)][k=32s+8(l>>4)+j], j=0..7 -> 4 dwords.
__global__ __launch_bounds__(256) void k_stats_partial(
        const float* __restrict__ x, float2* __restrict__ part,
        const float* __restrict__ gw, const float* __restrict__ uw,
        uint32_t* __restrict__ wfrag) {
    int blk = blockIdx.x;
    int t = threadIdx.x;
    if (blk < 16) {
        int idx = blk * 256 + t;                  // 0..4095
        int fi = idx >> 8, rem = idx & 255;
        int l = rem >> 2, d = rem & 3;
        int mt = fi >> 1, s = fi & 1;
        int m = 16 * mt + (l & 15);
        int k = 32 * s + 8 * (l >> 4) + 2 * d;
        const float* Wr = (m < 64) ? (gw + m * 64) : (uw + (m - 64) * 64);
        wfrag[idx] = f32_to_bf16_bits(Wr[k]) | (f32_to_bf16_bits(Wr[k + 1]) << 16);
    }
    const float4* p = (const float4*)(x + (size_t)blk * 65536);
    float s = 0.f, s2 = 0.f;
#pragma unroll 16
    for (int i = 0; i < 64; ++i) {
        float4 v = p[t + i * 256];
        s  += v.x + v.y + v.z + v.w;
        s2 += v.x * v.x + v.y * v.y + v.z * v.z + v.w * v.w;
    }
#pragma unroll
    for (int off = 32; off; off >>= 1) {
        s  += __shfl_down(s,  off, 64);
        s2 += __shfl_down(s2, off, 64);
    }
    __shared__ float2 red[4];
    int wid = t >> 6;
    if ((t & 63) == 0) red[wid] = make_float2(s, s2);
    __syncthreads();
    if (t == 0) {
        float a = 0.f, b2 = 0.f;
#pragma unroll
        for (int i = 0; i < 4; ++i) { a += red[i].x; b2 += red[i].y; }
        part[blk] = make_float2(a, b2);
    }
}

// ---------------- K1b: finalize stats -> per-(b,c) affine ------------------
__global__ __launch_bounds__(512) void k_stats_final(
        const float2* __restrict__ part,
        const float* __restrict__ gn_w, const float* __restrict__ gn_b,
        float2* __restrict__ aff) {
    __shared__ float2 st[64];
    int t = threadIdx.x;
    if (t < 64) {
        float s = 0.f, s2 = 0.f;
#pragma unroll
        for (int i = 0; i < 8; ++i) { float2 p = part[t * 8 + i]; s += p.x; s2 += p.y; }
        float inv  = 1.0f / (float)GROUPELEMS;
        float mu   = s * inv;
        float var  = s2 * inv - mu * mu;
        st[t] = make_float2(mu, rsqrtf(var + EPSV));
    }
    __syncthreads();
    int b = t >> 6, c = t & 63, g = c >> 3;
    float2 mr = st[b * 8 + g];
    float a  = mr.y * gn_w[c];
    aff[t] = make_float2(a, gn_b[c] - mr.x * a);
}

// ---------------- K2: MFMA row kernel — norm, convs, sigmoid, W-scan -------
// grid = B*H = 2048 blocks x 256. Two halves of 128 px per row.
// LDS: gvhn[128][65] (33280 B) + affs/bgs/bus (1024 B) = 34304 B -> 4 blk/CU.
// A fragments streamed from global wfrag (16 KiB, L1-hot) per nc-chunk with
// asm-laundered pointer (resident A-array spilled at launch_bounds(256,4)).
// pair stores TEMPORAL: L3 retains pair for k_hscan2's (single) read.
__global__ __launch_bounds__(256, 4) void k_row(
        const float* __restrict__ x,
        const uint32_t* __restrict__ wfrag,
        const float* __restrict__ gate_b, const float* __restrict__ upd_b,
        const float2* __restrict__ aff,
        uint32_t* __restrict__ pair) {
    __shared__ uint32_t gvhn[128 * 65];   // [px][dword], stride 65
    __shared__ float2 affs[64];
    __shared__ __align__(16) float bgs[64];
    __shared__ __align__(16) float bus[64];

    const int t = threadIdx.x;
    const int w = t >> 6, l = t & 63, q = l >> 4, r16 = l & 15;
    const int row = blockIdx.x;
    const int b = row >> 8, y = row & 255;
    const size_t rowoff = (size_t)b * CHW + (size_t)y * WW;

    if (t < 64) { affs[t] = aff[b * 64 + t]; bgs[t] = gate_b[t]; bus[t] = upd_b[t]; }
    __syncthreads();

    float s_carry = 0.f;
    for (int tau = 0; tau < 2; ++tau) {
        const int x0 = tau << 7;
        // ---- stage normalized bf16 tile: 8 float4 loads, 16 b32 LDS writes -
#pragma unroll
        for (int i = 0; i < 4; ++i) {
            int unit = i * 256 + t;          // 0..1023
            int c2 = unit >> 5, p4 = unit & 31;
            int c = c2 << 1, px = p4 << 2;
            const float* xp = x + rowoff + (size_t)c * HWSZ + x0 + px;
            float4 v0 = *(const float4*)xp;
            float4 v1 = *(const float4*)(xp + HWSZ);
            float2 a0 = affs[c], a1 = affs[c + 1];
            uint32_t base = px * 65 + c2;
            gvhn[base]       = f32_to_bf16_bits(v0.x * a0.x + a0.y)
                             | (f32_to_bf16_bits(v1.x * a1.x + a1.y) << 16);
            gvhn[base + 65]  = f32_to_bf16_bits(v0.y * a0.x + a0.y)
                             | (f32_to_bf16_bits(v1.y * a1.x + a1.y) << 16);
            gvhn[base + 130] = f32_to_bf16_bits(v0.z * a0.x + a0.y)
                             | (f32_to_bf16_bits(v1.z * a1.x + a1.y) << 16);
            gvhn[base + 195] = f32_to_bf16_bits(v0.w * a0.x + a0.y)
                             | (f32_to_bf16_bits(v1.w * a1.x + a1.y) << 16);
        }
        __syncthreads();

        // ---- MFMA: wave w owns local px [32w, 32w+32) = 2 N-chunks of 16 ---
#pragma unroll
        for (int nc = 0; nc < 2; ++nc) {
            int n_local = (w << 5) + (nc << 4) + r16;
            int based = n_local * 65 + 4 * q;
            U32x4 B0u, B1u;
#pragma unroll
            for (int d = 0; d < 4; ++d) B0u.u[d] = gvhn[based + d];        // k=8q..8q+7
#pragma unroll
            for (int d = 0; d < 4; ++d) B1u.u[d] = gvhn[based + 16 + d];   // +32
            // acc init = bias, read as aligned f32x4 broadcast from LDS
            f32x4 acc[8];
#pragma unroll
            for (int mt = 0; mt < 4; ++mt) {
                acc[mt]     = *(const f32x4*)(bgs + 16 * mt + 4 * q);
                acc[mt + 4] = *(const f32x4*)(bus + 16 * mt + 4 * q);
            }
            // laundered pointer: loads below cannot be hoisted out of nc/tau
            uintptr_t wfa = (uintptr_t)wfrag;
            asm volatile("" : "+s"(wfa));
            const uint32_t* wf = (const uint32_t*)wfa;
#pragma unroll
            for (int mt = 0; mt < 8; ++mt) {
                U32x4 a0, a1;
                a0.q = *(const uint4*)(wf + (((mt << 1) | 0) * 64 + l) * 4);
                a1.q = *(const uint4*)(wf + (((mt << 1) | 1) * 64 + l) * 4);
                acc[mt] = __builtin_amdgcn_mfma_f32_16x16x32_bf16(a0.v, B0u.v, acc[mt], 0, 0, 0);
                acc[mt] = __builtin_amdgcn_mfma_f32_16x16x32_bf16(a1.v, B1u.v, acc[mt], 0, 0, 0);
            }
            // epilogue: sigmoid + pack (g | (1-g)*u<<16) via v_perm
#pragma unroll
            for (int mt = 0; mt < 4; ++mt)
#pragma unroll
                for (int r = 0; r < 4; ++r) {
                    float ga = acc[mt][r];
                    float ua = acc[mt + 4][r];
                    float g  = 1.0f / (1.0f + __expf(-ga));
                    float vv = (1.0f - g) * ua;
                    uint32_t pk = __builtin_amdgcn_perm(__float_as_uint(vv),
                                                        __float_as_uint(g), 0x07060302u);
                    gvhn[n_local * 65 + 16 * mt + 4 * q + r] = pk;
                }
        }
        __syncthreads();

        // ---- W-scan: thread c (<64) serial over 128 px; banks 2-way -------
        if (t < 64) {
            float s = s_carry;
#pragma unroll 8
            for (int xi = 0; xi < 128; ++xi) {
                uint32_t pk = gvhn[xi * 65 + t];
                float g = __uint_as_float(pk << 16);
                float v = __uint_as_float(pk & 0xffff0000u);
                s = __builtin_fmaf(g, s, v);
                gvhn[xi * 65 + t] = __builtin_amdgcn_perm(__float_as_uint(s), pk, 0x07060100u);
            }
            s_carry = s;
        }
        __syncthreads();

        // ---- write packed (gate, hw): 8 x dwordx4 stores, coalesced -------
#pragma unroll
        for (int i = 0; i < 8; ++i) {
            int unit = i * 256 + t;          // 0..2047
            int c = unit >> 5, p4 = unit & 31;
            int px = p4 << 2;
            uint32_t bidx = px * 65 + c;
            u32x4 o;
            o.x = gvhn[bidx];
            o.y = gvhn[bidx + 65];
            o.z = gvhn[bidx + 130];
            o.w = gvhn[bidx + 195];
            *(u32x4*)(pair + rowoff + (size_t)c * HWSZ + x0 + px) = o;
        }
        __syncthreads();
    }
}

// ---------------- K3: fused segmented H-scan, pair register-resident -------
// One block per (b,c) image: 1024 threads = (col-group cg 0..63 of 4 cols) x
// (seg 0..15 of 16 rows). Each thread loads its 16 rows x 4 cols of pair as
// uint4 (16 B/lane, 1 KiB/wave) ONCE into 64 VGPRs, aggregates 4 column
// transforms (G,V), LDS-composes 16 segments -> incoming carry, then applies
// phase 2 entirely from registers (NO pair re-read - saves 128 MiB HBM).
// x loads / out stores are float4 NT (streaming, last use).
// Serial scan depth: 16 (was 64). VGPR ~ pk 64 + xv 16 + misc < 128 cap.
__global__ __launch_bounds__(1024) void k_hscan2(
        uint32_t* __restrict__ io, const float* __restrict__ x) {
    __shared__ float2 gvs[16][256];   // 32 KiB: per-(seg,col) aggregate
    __shared__ float  sins[16][256];  // 16 KiB: per-(seg,col) incoming carry
    const int t = threadIdx.x;
    const int cg = t & 63, seg = t >> 6;         // cols 4cg..4cg+3, rows 16seg..
    const size_t base = (size_t)blockIdx.x * HWSZ + (size_t)seg * 16 * WW + cg * 4;

    // phase 1: load 16 rows x uint4 into regs (NT: pair read exactly once)
    u32x4 pk[16];
#pragma unroll
    for (int j = 0; j < 16; ++j)
        pk[j] = __builtin_nontemporal_load((const u32x4*)(io + base + (size_t)j * WW));

    float G[4] = {1.f, 1.f, 1.f, 1.f}, V[4] = {0.f, 0.f, 0.f, 0.f};
#pragma unroll
    for (int j = 0; j < 16; ++j) {
#pragma unroll
        for (int c = 0; c < 4; ++c) {
            uint32_t p = pk[j][c];
            float g  = __uint_as_float(p << 16);
            float hw = __uint_as_float(p & 0xffff0000u);
            V[c] = __builtin_fmaf(g, V[c], (1.f - g) * hw);
            G[c] *= g;
        }
    }
#pragma unroll
    for (int c = 0; c < 4; ++c) gvs[seg][cg * 4 + c] = make_float2(G[c], V[c]);
    __syncthreads();

    // compose: 256 threads (one per col) scan the 16 segment transforms
    if (t < 256) {
        float s = 0.f;
#pragma unroll
        for (int sg = 0; sg < 16; ++sg) {
            sins[sg][t] = s;
            float2 gv = gvs[sg][t];
            s = __builtin_fmaf(gv.x, s, gv.y);
        }
    }
    __syncthreads();

    // phase 2: apply from registers + residual; NT stores (nobody reads out)
    float s0 = sins[seg][cg * 4 + 0];
    float s1 = sins[seg][cg * 4 + 1];
    float s2 = sins[seg][cg * 4 + 2];
    float s3 = sins[seg][cg * 4 + 3];
#pragma unroll
    for (int j = 0; j < 16; ++j) {
        f32x4 xv = __builtin_nontemporal_load((const f32x4*)(x + base + (size_t)j * WW));
        f32x4 res;
        {
            uint32_t p = pk[j][0];
            float g = __uint_as_float(p << 16), hw = __uint_as_float(p & 0xffff0000u);
            s0 = __builtin_fmaf(g, s0, (1.f - g) * hw); res[0] = xv[0] + s0;
        }
        {
            uint32_t p = pk[j][1];
            float g = __uint_as_float(p << 16), hw = __uint_as_float(p & 0xffff0000u);
            s1 = __builtin_fmaf(g, s1, (1.f - g) * hw); res[1] = xv[1] + s1;
        }
        {
            uint32_t p = pk[j][2];
            float g = __uint_as_float(p << 16), hw = __uint_as_float(p & 0xffff0000u);
            s2 = __builtin_fmaf(g, s2, (1.f - g) * hw); res[2] = xv[2] + s2;
        }
        {
            uint32_t p = pk[j][3];
            float g = __uint_as_float(p << 16), hw = __uint_as_float(p & 0xffff0000u);
            s3 = __builtin_fmaf(g, s3, (1.f - g) * hw); res[3] = xv[3] + s3;
        }
        __builtin_nontemporal_store(res, (f32x4*)((float*)io + base + (size_t)j * WW));
    }
}

extern "C" void kernel_launch(void* const* d_in, const int* in_sizes, int n_in,
                              void* d_out, int out_size, void* d_ws, size_t ws_size,
                              hipStream_t stream) {
    const float* x      = (const float*)d_in[0];
    const float* gn_w   = (const float*)d_in[1];
    const float* gn_b   = (const float*)d_in[2];
    const float* gate_w = (const float*)d_in[3];
    const float* gate_b = (const float*)d_in[4];
    const float* upd_w  = (const float*)d_in[5];
    const float* upd_b  = (const float*)d_in[6];

    char* ws = (char*)d_ws;
    float2*   part  = (float2*)(ws + WS_PART_OFF);
    float2*   aff   = (float2*)(ws + WS_AFF_OFF);
    uint32_t* wfrag = (uint32_t*)(ws + WS_WFRAG_OFF);
    uint32_t* pair  = (uint32_t*)d_out;   // packed (gate,hw); K3 rewrites in place

    k_stats_partial<<<512, 256, 0, stream>>>(x, part, gate_w, upd_w, wfrag);
    k_stats_final<<<1, 512, 0, stream>>>(part, gn_w, gn_b, aff);
    k_row<<<BB * HH, 256, 0, stream>>>(x, wfrag, gate_b, upd_b, aff, pair);
    k_hscan2<<<BB * CC, 1024, 0, stream>>>(pair, x);
}